// Round 4
// baseline (133.203 us; speedup 1.0000x reference)
//
#include <hip/hip_runtime.h>
#include <hip/hip_bf16.h>
#include <math.h>

#define GN 1024
#define GM 32
#define GD 512
#define NROW (GN*GM)   // 32768

// ---------------- ws layout (bytes) ----------------
#define WS_XB    0ull                  // bf16 [NROW][GD]  = 33554432 B
#define WS_SB    33554432ull           // bf16 [GN][GD]    =  1048576 B
#define WS_INVSN 34603008ull           // f32  [GN]        =     4096 B
#define WS_INVXN 34607104ull           // f32  [NROW]      =   131072 B
#define WS_CSOWN 34738176ull           // f32  [NROW]      =   131072 B
#define WS_PS    34869248ull           // f32  [NROW*16]   =  2097152 B

typedef __attribute__((ext_vector_type(8))) short bf16x8;
typedef __attribute__((ext_vector_type(4))) float f32x4;

// ---------------------------------------------------------------------------
// Kernel A: per speaker n — centroid sums, norms, own-centroid cosine,
// plus bf16 conversion of x and S for the MFMA GEMM.
// grid GN blocks, 512 threads.
// ---------------------------------------------------------------------------
__global__ __launch_bounds__(512) void prep_kernel(
    const float* __restrict__ x, const float* __restrict__ wp,
    const float* __restrict__ bp, char* __restrict__ wsb)
{
    __hip_bfloat16* xbw  = (__hip_bfloat16*)(wsb + WS_XB);
    __hip_bfloat16* Sbw  = (__hip_bfloat16*)(wsb + WS_SB);
    float* invSn = (float*)(wsb + WS_INVSN);
    float* invxn = (float*)(wsb + WS_INVXN);
    float* csown = (float*)(wsb + WS_CSOWN);

    const int n = blockIdx.x;
    const int d = threadIdx.x;           // 0..511
    const int lane = threadIdx.x & 63;
    const int wid  = threadIdx.x >> 6;   // 0..7

    __shared__ float sS[GD];
    __shared__ float red[8];
    __shared__ float sSn2;

    const float* xn_ = x + (size_t)n * GM * GD;

    // phase 1: column sums S[n,d] + bf16 conversion of x
    float Sd = 0.f;
    #pragma unroll
    for (int m = 0; m < GM; ++m) {
        float xv = xn_[m * GD + d];
        Sd += xv;
        xbw[(size_t)(n * GM + m) * GD + d] = __float2bfloat16(xv);
    }
    sS[d] = Sd;
    Sbw[(size_t)n * GD + d] = __float2bfloat16(Sd);

    // block reduce Sd^2 -> ||S||^2
    float p = Sd * Sd;
    #pragma unroll
    for (int off = 32; off > 0; off >>= 1) p += __shfl_down(p, off);
    if (lane == 0) red[wid] = p;
    __syncthreads();
    if (threadIdx.x == 0) {
        float s = 0.f;
        #pragma unroll
        for (int i = 0; i < 8; ++i) s += red[i];
        sSn2 = s;
        invSn[n] = rsqrtf(s);
    }
    __syncthreads();

    // phase 2: per-utterance norms + dot(x, S)
    const float w0 = wp[0], b0 = bp[0];
    const float Sn2 = sSn2;
    #pragma unroll
    for (int mm = 0; mm < 4; ++mm) {
        const int m = wid + mm * 8;
        float xn2 = 0.f, dn = 0.f;
        #pragma unroll
        for (int j = 0; j < 8; ++j) {
            float xv = xn_[m * GD + lane + 64 * j];
            float sv = sS[lane + 64 * j];
            xn2 += xv * xv;
            dn  += xv * sv;
        }
        #pragma unroll
        for (int off = 32; off > 0; off >>= 1) {
            xn2 += __shfl_down(xn2, off);
            dn  += __shfl_down(dn, off);
        }
        if (lane == 0) {
            float ixn = rsqrtf(xn2);
            float en2 = Sn2 - 2.f * dn + xn2;          // ||S - x||^2
            float cosown = (dn - xn2) * ixn * rsqrtf(en2);
            csown[n * GM + m] = w0 * fmaxf(cosown, 1e-6f) + b0;
            invxn[n * GM + m] = ixn;
        }
    }
}

// ---------------------------------------------------------------------------
// Kernel B: bf16 MFMA GEMM G = xb(32768x512) * Sb^T(512x1024).
// 128x128 tile / BK=32 / 4 waves (2x2) / 4x4 16x16x32 fragments per wave.
// Deep pipeline: 4 LDS buffers, prefetch distance 3, counted s_waitcnt
// vmcnt(12) (never 0 in steady state), raw s_barriers. Fully unrolled
// 16-step K loop. Fused fixed-shift partial-softmax epilogue.
// grid (256 rowblocks, 8 colblocks), 256 threads.
// ---------------------------------------------------------------------------
__global__ __launch_bounds__(256) void gemm_kernel(
    const float* __restrict__ wp, const float* __restrict__ bp,
    char* __restrict__ wsb)
{
    const __hip_bfloat16* xb  = (const __hip_bfloat16*)(wsb + WS_XB);
    const __hip_bfloat16* Sbm = (const __hip_bfloat16*)(wsb + WS_SB);
    const float* invSn = (const float*)(wsb + WS_INVSN);
    const float* invxn = (const float*)(wsb + WS_INVXN);
    const float* csown = (const float*)(wsb + WS_CSOWN);
    float* ps = (float*)(wsb + WS_PS);

    // slot s = kb*128 + row; each slot = 8 bf16 = 16 B (one fragment k-chunk)
    __shared__ __align__(16) __hip_bfloat16 Ab[4][512][8];
    __shared__ __align__(16) __hip_bfloat16 Bb[4][512][8];

    const int t    = threadIdx.x;
    const int w    = t >> 6;
    const int lane = t & 63;
    const int wr   = w >> 1, wc = w & 1;
    const int rbase = blockIdx.x * 128;
    const int cbase = blockIdx.y * 128;

    const int kb  = lane >> 4;   // k-group 0..3 (also C row-group)
    const int r16 = lane & 15;

    f32x4 acc[4][4] = {};

    // staging slots for this thread: s = p*256 + t, p = 0..1
    const int s0 = t, s1 = 256 + t;
    const int arow0 = rbase + (s0 & 127), akb0 = (s0 >> 7) * 8;
    const int arow1 = rbase + (s1 & 127), akb1 = (s1 >> 7) * 8;
    const int brow0 = cbase + (s0 & 127);
    const int brow1 = cbase + (s1 & 127);
    // wave-uniform LDS slot bases (HW adds lane*16B)
    const int base0 = (t >> 6) * 64;          // slots   0..255 region
    const int base1 = 256 + (t >> 6) * 64;    // slots 256..511 region

#define STAGE(buf, k0)                                                         \
    do {                                                                       \
        __builtin_amdgcn_global_load_lds(                                      \
            (const __attribute__((address_space(1))) void*)(xb +               \
                (size_t)arow0 * GD + (k0) + akb0),                             \
            (__attribute__((address_space(3))) void*)&Ab[buf][base0][0],       \
            16, 0, 0);                                                         \
        __builtin_amdgcn_global_load_lds(                                      \
            (const __attribute__((address_space(1))) void*)(xb +               \
                (size_t)arow1 * GD + (k0) + akb1),                             \
            (__attribute__((address_space(3))) void*)&Ab[buf][base1][0],       \
            16, 0, 0);                                                         \
        __builtin_amdgcn_global_load_lds(                                      \
            (const __attribute__((address_space(1))) void*)(Sbm +              \
                (size_t)brow0 * GD + (k0) + akb0),                             \
            (__attribute__((address_space(3))) void*)&Bb[buf][base0][0],       \
            16, 0, 0);                                                         \
        __builtin_amdgcn_global_load_lds(                                      \
            (const __attribute__((address_space(1))) void*)(Sbm +              \
                (size_t)brow1 * GD + (k0) + akb1),                             \
            (__attribute__((address_space(3))) void*)&Bb[buf][base1][0],       \
            16, 0, 0);                                                         \
    } while (0)

#define WAITVM_(N) asm volatile("s_waitcnt vmcnt(" #N ")" ::: "memory")
#define WAITVM(N)  WAITVM_(N)

    auto compute = [&](int buf) {
        bf16x8 af[4], bfr[4];
        #pragma unroll
        for (int mi = 0; mi < 4; ++mi)
            af[mi] = *(const bf16x8*)&Ab[buf][kb * 128 + wr * 64 + mi * 16 + r16][0];
        #pragma unroll
        for (int nj = 0; nj < 4; ++nj)
            bfr[nj] = *(const bf16x8*)&Bb[buf][kb * 128 + wc * 64 + nj * 16 + r16][0];
        #pragma unroll
        for (int mi = 0; mi < 4; ++mi)
            #pragma unroll
            for (int nj = 0; nj < 4; ++nj)
                acc[mi][nj] = __builtin_amdgcn_mfma_f32_16x16x32_bf16(
                    af[mi], bfr[nj], acc[mi][nj], 0, 0, 0);
    };

    // Per-step: stage tile ks+3, wait until tile ks's 4 loads retired
    // (vmcnt = 4 * tiles-in-flight-ahead), barrier, compute, barrier.
#define KSTEP(ks, vm)                                                          \
    do {                                                                       \
        if ((ks) + 3 < 16) STAGE(((ks) + 3) & 3, ((ks) + 3) * 32);             \
        WAITVM(vm);                                                            \
        __builtin_amdgcn_s_barrier();                                          \
        __builtin_amdgcn_sched_barrier(0);                                     \
        compute((ks) & 3);                                                     \
        asm volatile("s_waitcnt lgkmcnt(0)" ::: "memory");                     \
        __builtin_amdgcn_s_barrier();                                          \
    } while (0)

    // prologue: 3 tiles in flight
    STAGE(0, 0);
    STAGE(1, 32);
    STAGE(2, 64);

    KSTEP(0, 12);  KSTEP(1, 12);  KSTEP(2, 12);  KSTEP(3, 12);
    KSTEP(4, 12);  KSTEP(5, 12);  KSTEP(6, 12);  KSTEP(7, 12);
    KSTEP(8, 12);  KSTEP(9, 12);  KSTEP(10, 12); KSTEP(11, 12);
    KSTEP(12, 12); KSTEP(13, 8);  KSTEP(14, 4);  KSTEP(15, 0);

#undef KSTEP
#undef WAITVM
#undef WAITVM_
#undef STAGE

    // ---- fused epilogue: fixed-shift partial softmax over 64-col wave tile
    const float w0 = wp[0], b0 = bp[0];
    const float C = fmaxf(w0 * 1e-6f + b0, w0 + b0);   // logit upper bound
    const int pcol = blockIdx.y * 2 + wc;              // 0..15 partial slot
    float isn[4];
    #pragma unroll
    for (int nj = 0; nj < 4; ++nj)
        isn[nj] = invSn[cbase + wc * 64 + nj * 16 + r16];

    #pragma unroll
    for (int mi = 0; mi < 4; ++mi) {
        #pragma unroll
        for (int r = 0; r < 4; ++r) {
            const int row = rbase + wr * 64 + mi * 16 + kb * 4 + r;
            const float ixn = invxn[row];
            const float cso = csown[row];
            const int own = row >> 5;
            float se = 0.f;
            #pragma unroll
            for (int nj = 0; nj < 4; ++nj) {
                const int col = cbase + wc * 64 + nj * 16 + r16;
                float cs = w0 * fmaxf(acc[mi][nj][r] * ixn * isn[nj], 1e-6f) + b0;
                cs = (col == own) ? cso : cs;
                se += __expf(cs - C);
            }
            #pragma unroll
            for (int off = 1; off < 16; off <<= 1)
                se += __shfl_xor(se, off, 16);
            if (r16 == 0)
                ps[(size_t)row * 16 + pcol] = se;
        }
    }
}

// ---------------------------------------------------------------------------
// Kernel C: combine 16 sum-partials per row (shared fixed shift C),
// loss = C + log(sum) - cs_own, mean-reduce into d_out[0].
// ---------------------------------------------------------------------------
__global__ __launch_bounds__(256) void finalize_kernel(
    const char* __restrict__ wsb, const float* __restrict__ wp,
    const float* __restrict__ bp, float* __restrict__ out)
{
    const float* csown = (const float*)(wsb + WS_CSOWN);
    const float* ps    = (const float*)(wsb + WS_PS);

    const float w0 = wp[0], b0 = bp[0];
    const float C = fmaxf(w0 * 1e-6f + b0, w0 + b0);

    const int row = blockIdx.x * 256 + threadIdx.x;
    float s = 0.f;
    #pragma unroll
    for (int i = 0; i < 16; ++i) s += ps[(size_t)row * 16 + i];
    float loss = C + logf(s) - csown[row];

    const int lane = threadIdx.x & 63;
    const int wid  = threadIdx.x >> 6;
    __shared__ float red[4];
    #pragma unroll
    for (int off = 32; off > 0; off >>= 1) loss += __shfl_down(loss, off);
    if (lane == 0) red[wid] = loss;
    __syncthreads();
    if (threadIdx.x == 0) {
        float sum = red[0] + red[1] + red[2] + red[3];
        atomicAdd(out, sum * (1.f / (GN * GM)));
    }
}

extern "C" void kernel_launch(void* const* d_in, const int* in_sizes, int n_in,
                              void* d_out, int out_size, void* d_ws, size_t ws_size,
                              hipStream_t stream)
{
    const float* x  = (const float*)d_in[0];
    const float* wp = (const float*)d_in[1];
    const float* bp = (const float*)d_in[2];
    float* out = (float*)d_out;
    char* wsb  = (char*)d_ws;

    hipMemsetAsync(d_out, 0, sizeof(float), stream);

    prep_kernel<<<GN, 512, 0, stream>>>(x, wp, bp, wsb);

    dim3 ggrid(256, 8);
    gemm_kernel<<<ggrid, 256, 0, stream>>>(wp, bp, wsb);

    finalize_kernel<<<128, 256, 0, stream>>>(wsb, wp, bp, out);
}

// Round 5
// 116.741 us; speedup vs baseline: 1.1410x; 1.1410x over previous
//
#include <hip/hip_runtime.h>
#include <hip/hip_bf16.h>
#include <math.h>

#define GN 1024
#define GM 32
#define GD 512
#define NROW (GN*GM)   // 32768

// ---------------- ws layout (bytes) ----------------
#define WS_XB    0ull                  // bf16 [NROW][GD]  = 33554432 B
#define WS_SB    33554432ull           // bf16 [GN][GD]    =  1048576 B
#define WS_INVSN 34603008ull           // f32  [GN]        =     4096 B
#define WS_INVXN 34607104ull           // f32  [NROW]      =   131072 B
#define WS_CSOWN 34738176ull           // f32  [NROW]      =   131072 B
#define WS_PS    34869248ull           // f32  [NROW*16]   =  2097152 B

typedef __attribute__((ext_vector_type(8))) short bf16x8;
typedef __attribute__((ext_vector_type(4))) float f32x4;

// ---------------------------------------------------------------------------
// Kernel A: per speaker n — centroid sums, norms, own-centroid cosine,
// plus bf16 conversion of x and S for the MFMA GEMM.
// grid GN blocks, 512 threads.
// ---------------------------------------------------------------------------
__global__ __launch_bounds__(512) void prep_kernel(
    const float* __restrict__ x, const float* __restrict__ wp,
    const float* __restrict__ bp, char* __restrict__ wsb)
{
    __hip_bfloat16* xbw  = (__hip_bfloat16*)(wsb + WS_XB);
    __hip_bfloat16* Sbw  = (__hip_bfloat16*)(wsb + WS_SB);
    float* invSn = (float*)(wsb + WS_INVSN);
    float* invxn = (float*)(wsb + WS_INVXN);
    float* csown = (float*)(wsb + WS_CSOWN);

    const int n = blockIdx.x;
    const int d = threadIdx.x;           // 0..511
    const int lane = threadIdx.x & 63;
    const int wid  = threadIdx.x >> 6;   // 0..7

    __shared__ float sS[GD];
    __shared__ float red[8];
    __shared__ float sSn2;

    const float* xn_ = x + (size_t)n * GM * GD;

    // phase 1: column sums S[n,d] + bf16 conversion of x
    float Sd = 0.f;
    #pragma unroll
    for (int m = 0; m < GM; ++m) {
        float xv = xn_[m * GD + d];
        Sd += xv;
        xbw[(size_t)(n * GM + m) * GD + d] = __float2bfloat16(xv);
    }
    sS[d] = Sd;
    Sbw[(size_t)n * GD + d] = __float2bfloat16(Sd);

    // block reduce Sd^2 -> ||S||^2
    float p = Sd * Sd;
    #pragma unroll
    for (int off = 32; off > 0; off >>= 1) p += __shfl_down(p, off);
    if (lane == 0) red[wid] = p;
    __syncthreads();
    if (threadIdx.x == 0) {
        float s = 0.f;
        #pragma unroll
        for (int i = 0; i < 8; ++i) s += red[i];
        sSn2 = s;
        invSn[n] = rsqrtf(s);
    }
    __syncthreads();

    // phase 2: per-utterance norms + dot(x, S)
    const float w0 = wp[0], b0 = bp[0];
    const float Sn2 = sSn2;
    #pragma unroll
    for (int mm = 0; mm < 4; ++mm) {
        const int m = wid + mm * 8;
        float xn2 = 0.f, dn = 0.f;
        #pragma unroll
        for (int j = 0; j < 8; ++j) {
            float xv = xn_[m * GD + lane + 64 * j];
            float sv = sS[lane + 64 * j];
            xn2 += xv * xv;
            dn  += xv * sv;
        }
        #pragma unroll
        for (int off = 32; off > 0; off >>= 1) {
            xn2 += __shfl_down(xn2, off);
            dn  += __shfl_down(dn, off);
        }
        if (lane == 0) {
            float ixn = rsqrtf(xn2);
            float en2 = Sn2 - 2.f * dn + xn2;          // ||S - x||^2
            float cosown = (dn - xn2) * ixn * rsqrtf(en2);
            csown[n * GM + m] = w0 * fmaxf(cosown, 1e-6f) + b0;
            invxn[n * GM + m] = ixn;
        }
    }
}

// ---------------------------------------------------------------------------
// Kernel B: bf16 MFMA GEMM G = xb(32768x512) * Sb^T(512x1024).
// 128x128 tile / BK=32 / 4 waves (2x2) / 4x4 16x16x32 fragments per wave.
// 3 LDS buffers (48 KB -> 3 blocks/CU), prefetch distance 2, ONE raw
// s_barrier per K-step, counted s_waitcnt vmcnt(4) (drain only at the
// last step). XCD-aware bid swizzle: each XCD owns 32 contiguous
// row-panels; the 8 col-blocks of a row-panel are adjacent in dispatch
// order so the A-panel is fetched into one L2 once, hit 8x.
// Fused fixed-shift partial-softmax epilogue. grid 2048 blocks, 256 thr.
// ---------------------------------------------------------------------------
__global__ __launch_bounds__(256) void gemm_kernel(
    const float* __restrict__ wp, const float* __restrict__ bp,
    char* __restrict__ wsb)
{
    const __hip_bfloat16* xb  = (const __hip_bfloat16*)(wsb + WS_XB);
    const __hip_bfloat16* Sbm = (const __hip_bfloat16*)(wsb + WS_SB);
    const float* invSn = (const float*)(wsb + WS_INVSN);
    const float* invxn = (const float*)(wsb + WS_INVXN);
    const float* csown = (const float*)(wsb + WS_CSOWN);
    float* ps = (float*)(wsb + WS_PS);

    // slot s = kb*128 + row; each slot = 8 bf16 = 16 B (one fragment k-chunk)
    __shared__ __align__(16) __hip_bfloat16 Ab[3][512][8];
    __shared__ __align__(16) __hip_bfloat16 Bb[3][512][8];

    // XCD swizzle: hw xcd = bid & 7 owns row-panels [xcd*32, xcd*32+32),
    // walking col-panels fastest.
    const int bid  = blockIdx.x;          // 0..2047
    const int u    = bid >> 3;            // 0..255
    const int rowp = (bid & 7) * 32 + (u >> 3);
    const int colp = u & 7;
    const int rbase = rowp * 128;
    const int cbase = colp * 128;

    const int t    = threadIdx.x;
    const int w    = t >> 6;
    const int lane = t & 63;
    const int wr   = w >> 1, wc = w & 1;

    const int kb  = lane >> 4;   // k-group 0..3 (also C row-group)
    const int r16 = lane & 15;

    f32x4 acc[4][4] = {};

    // staging slots for this thread: s = p*256 + t, p = 0..1
    const int s0 = t, s1 = 256 + t;
    const int arow0 = rbase + (s0 & 127), akb0 = (s0 >> 7) * 8;
    const int arow1 = rbase + (s1 & 127), akb1 = (s1 >> 7) * 8;
    const int brow0 = cbase + (s0 & 127);
    const int brow1 = cbase + (s1 & 127);
    // wave-uniform LDS slot bases (HW adds lane*16B)
    const int base0 = (t >> 6) * 64;          // slots   0..255 region
    const int base1 = 256 + (t >> 6) * 64;    // slots 256..511 region

#define STAGE(buf, ks)                                                        \
    do {                                                                      \
        const int k0_ = (ks) * 32;                                            \
        __builtin_amdgcn_global_load_lds(                                     \
            (const __attribute__((address_space(1))) void*)(xb +              \
                (size_t)arow0 * GD + k0_ + akb0),                             \
            (__attribute__((address_space(3))) void*)&Ab[buf][base0][0],      \
            16, 0, 0);                                                        \
        __builtin_amdgcn_global_load_lds(                                     \
            (const __attribute__((address_space(1))) void*)(xb +              \
                (size_t)arow1 * GD + k0_ + akb1),                             \
            (__attribute__((address_space(3))) void*)&Ab[buf][base1][0],      \
            16, 0, 0);                                                        \
        __builtin_amdgcn_global_load_lds(                                     \
            (const __attribute__((address_space(1))) void*)(Sbm +             \
                (size_t)brow0 * GD + k0_ + akb0),                             \
            (__attribute__((address_space(3))) void*)&Bb[buf][base0][0],      \
            16, 0, 0);                                                        \
        __builtin_amdgcn_global_load_lds(                                     \
            (const __attribute__((address_space(1))) void*)(Sbm +             \
                (size_t)brow1 * GD + k0_ + akb1),                             \
            (__attribute__((address_space(3))) void*)&Bb[buf][base1][0],      \
            16, 0, 0);                                                        \
    } while (0)

    auto compute = [&](int buf) {
        bf16x8 af[4], bfr[4];
        #pragma unroll
        for (int mi = 0; mi < 4; ++mi)
            af[mi] = *(const bf16x8*)&Ab[buf][kb * 128 + wr * 64 + mi * 16 + r16][0];
        #pragma unroll
        for (int nj = 0; nj < 4; ++nj)
            bfr[nj] = *(const bf16x8*)&Bb[buf][kb * 128 + wc * 64 + nj * 16 + r16][0];
        #pragma unroll
        for (int mi = 0; mi < 4; ++mi)
            #pragma unroll
            for (int nj = 0; nj < 4; ++nj)
                acc[mi][nj] = __builtin_amdgcn_mfma_f32_16x16x32_bf16(
                    af[mi], bfr[nj], acc[mi][nj], 0, 0, 0);
    };

#define WAITVM_(N) asm volatile("s_waitcnt vmcnt(" #N ")" ::: "memory")
#define BARRIER()  asm volatile("s_barrier" ::: "memory")

    // Step ks: wait tile ks landed (counted), barrier, prefetch tile ks+2
    // into buf (ks+2)%3 (safe: that buf was last read at step ks-1, which
    // every wave finished before this barrier), compute tile ks.
#define KSTEP(ks, vm)                                                         \
    do {                                                                      \
        WAITVM_(vm);                                                          \
        BARRIER();                                                            \
        if ((ks) + 2 < 16) STAGE(((ks) + 2) % 3, (ks) + 2);                   \
        compute((ks) % 3);                                                    \
    } while (0)

    // prologue: 2 tiles in flight
    STAGE(0, 0);
    STAGE(1, 1);

    KSTEP(0, 4);   KSTEP(1, 4);   KSTEP(2, 4);   KSTEP(3, 4);
    KSTEP(4, 4);   KSTEP(5, 4);   KSTEP(6, 4);   KSTEP(7, 4);
    KSTEP(8, 4);   KSTEP(9, 4);   KSTEP(10, 4);  KSTEP(11, 4);
    KSTEP(12, 4);  KSTEP(13, 4);  KSTEP(14, 4);  KSTEP(15, 0);

#undef KSTEP
#undef WAITVM_
#undef BARRIER
#undef STAGE

    // ---- fused epilogue: fixed-shift partial softmax over 64-col wave tile
    const float w0 = wp[0], b0 = bp[0];
    const float C = fmaxf(w0 * 1e-6f + b0, w0 + b0);   // logit upper bound
    const int pcol = colp * 2 + wc;                    // 0..15 partial slot
    float isn[4];
    #pragma unroll
    for (int nj = 0; nj < 4; ++nj)
        isn[nj] = invSn[cbase + wc * 64 + nj * 16 + r16];

    #pragma unroll
    for (int mi = 0; mi < 4; ++mi) {
        #pragma unroll
        for (int r = 0; r < 4; ++r) {
            const int row = rbase + wr * 64 + mi * 16 + kb * 4 + r;
            const float ixn = invxn[row];
            const float cso = csown[row];
            const int own = row >> 5;
            float se = 0.f;
            #pragma unroll
            for (int nj = 0; nj < 4; ++nj) {
                const int col = cbase + wc * 64 + nj * 16 + r16;
                float cs = w0 * fmaxf(acc[mi][nj][r] * ixn * isn[nj], 1e-6f) + b0;
                cs = (col == own) ? cso : cs;
                se += __expf(cs - C);
            }
            #pragma unroll
            for (int off = 1; off < 16; off <<= 1)
                se += __shfl_xor(se, off, 16);
            if (r16 == 0)
                ps[(size_t)row * 16 + pcol] = se;
        }
    }
}

// ---------------------------------------------------------------------------
// Kernel C: combine 16 sum-partials per row (shared fixed shift C),
// loss = C + log(sum) - cs_own, mean-reduce into d_out[0].
// ---------------------------------------------------------------------------
__global__ __launch_bounds__(256) void finalize_kernel(
    const char* __restrict__ wsb, const float* __restrict__ wp,
    const float* __restrict__ bp, float* __restrict__ out)
{
    const float* csown = (const float*)(wsb + WS_CSOWN);
    const float* ps    = (const float*)(wsb + WS_PS);

    const float w0 = wp[0], b0 = bp[0];
    const float C = fmaxf(w0 * 1e-6f + b0, w0 + b0);

    const int row = blockIdx.x * 256 + threadIdx.x;
    float s = 0.f;
    #pragma unroll
    for (int i = 0; i < 16; ++i) s += ps[(size_t)row * 16 + i];
    float loss = C + logf(s) - csown[row];

    const int lane = threadIdx.x & 63;
    const int wid  = threadIdx.x >> 6;
    __shared__ float red[4];
    #pragma unroll
    for (int off = 32; off > 0; off >>= 1) loss += __shfl_down(loss, off);
    if (lane == 0) red[wid] = loss;
    __syncthreads();
    if (threadIdx.x == 0) {
        float sum = red[0] + red[1] + red[2] + red[3];
        atomicAdd(out, sum * (1.f / (GN * GM)));
    }
}

extern "C" void kernel_launch(void* const* d_in, const int* in_sizes, int n_in,
                              void* d_out, int out_size, void* d_ws, size_t ws_size,
                              hipStream_t stream)
{
    const float* x  = (const float*)d_in[0];
    const float* wp = (const float*)d_in[1];
    const float* bp = (const float*)d_in[2];
    float* out = (float*)d_out;
    char* wsb  = (char*)d_ws;

    hipMemsetAsync(d_out, 0, sizeof(float), stream);

    prep_kernel<<<GN, 512, 0, stream>>>(x, wp, bp, wsb);

    gemm_kernel<<<2048, 256, 0, stream>>>(wp, bp, wsb);

    finalize_kernel<<<128, 256, 0, stream>>>(wsb, wp, bp, out);
}